// Round 1
// baseline (216.948 us; speedup 1.0000x reference)
//
#include <hip/hip_runtime.h>
#include <math.h>

typedef _Float16 half8_t __attribute__((ext_vector_type(8)));
typedef _Float16 half4_t __attribute__((ext_vector_type(4)));
typedef float f32x4 __attribute__((ext_vector_type(4)));

#define MFMA16(a, b, c) __builtin_amdgcn_mfma_f32_16x16x32_f16((a), (b), (c), 0, 0, 0)

// log2(e) / sqrt(128): fold softmax scale AND exp->exp2 conversion into q.
#define SCALE_Q (0.08838834764831845f * 1.44269504088896340736f)

// ---------------------------------------------------------------------------
// Kernel 0: W [512][128] fp32  ->  Wt [128][512] fp16   (x3 for q,k,v)
// ---------------------------------------------------------------------------
__global__ __launch_bounds__(256) void wt_kernel(const float* __restrict__ Wq,
                                                 const float* __restrict__ Wk,
                                                 const float* __restrict__ Wv,
                                                 _Float16* __restrict__ WtAll) {
    int y = blockIdx.y;
    const float* W = (y == 0) ? Wq : (y == 1) ? Wk : Wv;
    int idx = blockIdx.x * 256 + threadIdx.x;   // 0..65535, coalesced read
    int kk = idx >> 7;                           // d_in   0..511
    int d  = idx & 127;                          // d_att  0..127
    WtAll[y * 65536 + d * 512 + kk] = (_Float16)W[idx];
}

// ---------------------------------------------------------------------------
// Kernel 1: projection GEMM.  C[16384][128] = X[16384][512] @ W + b
// grid.y selects q/k/v. q scaled by SCALE_Q. v written transposed [b][d][s].
// ---------------------------------------------------------------------------
__global__ __launch_bounds__(256) void proj_kernel(
    const float* __restrict__ q_in, const float* __restrict__ k_in,
    const float* __restrict__ v_in, const _Float16* __restrict__ WtAll,
    const float* __restrict__ biasq, const float* __restrict__ biask,
    const float* __restrict__ biasv,
    _Float16* __restrict__ qbuf, _Float16* __restrict__ kbuf,
    _Float16* __restrict__ vtbuf) {
    int y = blockIdx.y;
    const float* x = (y == 0) ? q_in : (y == 1) ? k_in : v_in;
    const _Float16* Wt = WtAll + y * 65536;
    const float* bias = (y == 0) ? biasq : (y == 1) ? biask : biasv;
    int row0 = blockIdx.x * 128;

    __shared__ _Float16 smem[17408];   // 34.8 KB; staging overlaid w/ epilogue
    _Float16* As = smem;               // [128][40]  (BK=32 +8 pad)
    _Float16* Ws = smem + 5120;        // [128][40]  (W^T tile: [d_att][k])

    int tid = threadIdx.x;
    int wave = tid >> 6, lane = tid & 63, quad = lane >> 4, l16 = lane & 15;
    int wm = (wave & 1) * 64, wn = (wave >> 1) * 64;
    int arow = tid >> 1, acol = (tid & 1) * 16;

    f32x4 acc[4][4] = {};

    for (int kb = 0; kb < 512; kb += 32) {
        __syncthreads();
        // stage A: 128 rows x 32 k, fp32 -> fp16
        const float4* ap =
            (const float4*)(x + (size_t)(row0 + arow) * 512 + kb + acol);
        float4 a0 = ap[0], a1 = ap[1], a2 = ap[2], a3 = ap[3];
        // stage Wt: 128 d_att rows x 32 k (already fp16)
        const half8_t* wp = (const half8_t*)(Wt + arow * 512 + kb + acol);
        half8_t w0 = wp[0], w1 = wp[1];
        half8_t h0, h1;
        h0[0] = (_Float16)a0.x; h0[1] = (_Float16)a0.y;
        h0[2] = (_Float16)a0.z; h0[3] = (_Float16)a0.w;
        h0[4] = (_Float16)a1.x; h0[5] = (_Float16)a1.y;
        h0[6] = (_Float16)a1.z; h0[7] = (_Float16)a1.w;
        h1[0] = (_Float16)a2.x; h1[1] = (_Float16)a2.y;
        h1[2] = (_Float16)a2.z; h1[3] = (_Float16)a2.w;
        h1[4] = (_Float16)a3.x; h1[5] = (_Float16)a3.y;
        h1[6] = (_Float16)a3.z; h1[7] = (_Float16)a3.w;
        *(half8_t*)&As[arow * 40 + acol]     = h0;
        *(half8_t*)&As[arow * 40 + acol + 8] = h1;
        *(half8_t*)&Ws[arow * 40 + acol]     = w0;
        *(half8_t*)&Ws[arow * 40 + acol + 8] = w1;
        __syncthreads();

        half8_t af[4], bf[4];
        for (int mt = 0; mt < 4; mt++)
            af[mt] = *(const half8_t*)&As[(wm + mt * 16 + l16) * 40 + quad * 8];
        for (int nt = 0; nt < 4; nt++)
            bf[nt] = *(const half8_t*)&Ws[(wn + nt * 16 + l16) * 40 + quad * 8];
        for (int mt = 0; mt < 4; mt++)
            for (int nt = 0; nt < 4; nt++)
                acc[mt][nt] = MFMA16(af[mt], bf[nt], acc[mt][nt]);
    }
    __syncthreads();

    // Epilogue: bias + scale, assemble tile in LDS, coalesced store.
    float scale = (y == 0) ? SCALE_Q : 1.0f;
    if (y < 2) {
        // row-major [s][d] tile in smem[128][136]
        for (int mt = 0; mt < 4; mt++)
            for (int nt = 0; nt < 4; nt++) {
                int d = wn + nt * 16 + l16;
                float b = bias[d];
                for (int r = 0; r < 4; r++)
                    smem[(wm + mt * 16 + quad * 4 + r) * 136 + d] =
                        (_Float16)((acc[mt][nt][r] + b) * scale);
            }
    } else {
        // transposed [d][s] tile in smem[128][136]
        for (int mt = 0; mt < 4; mt++)
            for (int nt = 0; nt < 4; nt++) {
                int d = wn + nt * 16 + l16;
                float b = bias[d];
                half4_t pk;
                for (int r = 0; r < 4; r++)
                    pk[r] = (_Float16)(acc[mt][nt][r] + b);
                *(half4_t*)&smem[d * 136 + wm + mt * 16 + quad * 4] = pk;
            }
    }
    __syncthreads();
    int srow = tid >> 1, scol = (tid & 1) * 64;
    if (y < 2) {
        _Float16* outp =
            ((y == 0) ? qbuf : kbuf) + (size_t)(row0 + srow) * 128 + scol;
        for (int i = 0; i < 8; i++)
            *(half8_t*)(outp + i * 8) =
                *(const half8_t*)&smem[srow * 136 + scol + i * 8];
    } else {
        int bbn = row0 >> 11, s0 = row0 & 2047;
        _Float16* outp =
            vtbuf + ((size_t)bbn * 128 + srow) * 2048 + s0 + scol;
        for (int i = 0; i < 8; i++)
            *(half8_t*)(outp + i * 8) =
                *(const half8_t*)&smem[srow * 136 + scol + i * 8];
    }
}

// ---------------------------------------------------------------------------
// Kernel 2: flash attention.  1 block = 64 q rows (4 waves x 16 q).
// S^T = K Q^T via MFMA (both operands row-contiguous); online softmax;
// P^T -> per-wave LDS; O += P V with V^T tiles.
// ---------------------------------------------------------------------------
__global__ __launch_bounds__(256) void attn_kernel(
    const _Float16* __restrict__ qbuf, const _Float16* __restrict__ kbuf,
    const _Float16* __restrict__ vtbuf, float* __restrict__ out) {
    int bb = blockIdx.x >> 5;
    int q0 = (blockIdx.x & 31) * 64;
    int tid = threadIdx.x, wave = tid >> 6, lane = tid & 63;
    int quad = lane >> 4, l16 = lane & 15;

    __shared__ _Float16 smem[31232];     // 62.4 KB
    _Float16* Qs = smem;                 // [64][136]
    _Float16* Ks = smem + 8704;          // [64][136]   (BKV=64 keys)
    _Float16* Vs = smem + 17408;         // [128][72]   (V^T: [d][key])
    _Float16* Pt = smem + 26624 + wave * 1152;   // [16][72] per wave

    // Load Q tile once: 64 rows x 128 d
    {
        int r = tid >> 2, c = (tid & 3) * 32;
        const half8_t* src =
            (const half8_t*)(qbuf + ((size_t)bb * 2048 + q0 + r) * 128 + c);
        half8_t v0 = src[0], v1 = src[1], v2 = src[2], v3 = src[3];
        *(half8_t*)&Qs[r * 136 + c]      = v0;
        *(half8_t*)&Qs[r * 136 + c + 8]  = v1;
        *(half8_t*)&Qs[r * 136 + c + 16] = v2;
        *(half8_t*)&Qs[r * 136 + c + 24] = v3;
    }
    __syncthreads();
    half8_t qf[4];
    for (int kc = 0; kc < 4; kc++)
        qf[kc] = *(const half8_t*)&Qs[(wave * 16 + l16) * 136 + kc * 32 + quad * 8];

    f32x4 o[8] = {};
    float m = -INFINITY, l = 0.0f;

    const _Float16* kbase = kbuf + (size_t)bb * 2048 * 128;
    const _Float16* vbase = vtbuf + (size_t)bb * 128 * 2048;

    int krow = tid >> 2, kcol = (tid & 3) * 32;   // K stage: 64 x 128
    int vrow = tid >> 1, vcol = (tid & 1) * 32;   // V stage: 128 x 64

    for (int kv = 0; kv < 2048; kv += 64) {
        __syncthreads();
        {
            const half8_t* ksrc =
                (const half8_t*)(kbase + (size_t)(kv + krow) * 128 + kcol);
            half8_t k0 = ksrc[0], k1 = ksrc[1], k2 = ksrc[2], k3 = ksrc[3];
            *(half8_t*)&Ks[krow * 136 + kcol]      = k0;
            *(half8_t*)&Ks[krow * 136 + kcol + 8]  = k1;
            *(half8_t*)&Ks[krow * 136 + kcol + 16] = k2;
            *(half8_t*)&Ks[krow * 136 + kcol + 24] = k3;
            const half8_t* vsrc =
                (const half8_t*)(vbase + (size_t)vrow * 2048 + kv + vcol);
            half8_t x0 = vsrc[0], x1 = vsrc[1], x2 = vsrc[2], x3 = vsrc[3];
            *(half8_t*)&Vs[vrow * 72 + vcol]      = x0;
            *(half8_t*)&Vs[vrow * 72 + vcol + 8]  = x1;
            *(half8_t*)&Vs[vrow * 72 + vcol + 16] = x2;
            *(half8_t*)&Vs[vrow * 72 + vcol + 24] = x3;
        }
        __syncthreads();

        // S^T[key][q] = K Q^T   (4 key-subtiles x 16)
        f32x4 sf[4];
        for (int kt = 0; kt < 4; kt++) {
            f32x4 a = {0.f, 0.f, 0.f, 0.f};
            for (int kc = 0; kc < 4; kc++) {
                half8_t kf = *(const half8_t*)&Ks[(kt * 16 + l16) * 136 +
                                                  kc * 32 + quad * 8];
                a = MFMA16(kf, qf[kc], a);
            }
            sf[kt] = a;
        }
        // online softmax over this tile's 64 keys (per q = l16)
        float mx = -INFINITY;
        for (int kt = 0; kt < 4; kt++)
            for (int r = 0; r < 4; r++) mx = fmaxf(mx, sf[kt][r]);
        mx = fmaxf(mx, __shfl_xor(mx, 16, 64));
        mx = fmaxf(mx, __shfl_xor(mx, 32, 64));
        float mn = fmaxf(m, mx);
        float alpha = exp2f(m - mn);
        float rs = 0.0f;
        for (int kt = 0; kt < 4; kt++) {
            half4_t pk;
            for (int r = 0; r < 4; r++) {
                float p = exp2f(sf[kt][r] - mn);
                rs += p;
                pk[r] = (_Float16)p;
            }
            *(half4_t*)&Pt[l16 * 72 + kt * 16 + quad * 4] = pk;
        }
        rs += __shfl_xor(rs, 16, 64);
        rs += __shfl_xor(rs, 32, 64);
        l = l * alpha + rs;
        m = mn;

        // rescale O: alpha for row q' = quad*4+r lives at lane q'
        float ar0 = __shfl(alpha, quad * 4 + 0, 64);
        float ar1 = __shfl(alpha, quad * 4 + 1, 64);
        float ar2 = __shfl(alpha, quad * 4 + 2, 64);
        float ar3 = __shfl(alpha, quad * 4 + 3, 64);
        for (int t = 0; t < 8; t++) {
            o[t][0] *= ar0; o[t][1] *= ar1;
            o[t][2] *= ar2; o[t][3] *= ar3;
        }
        // O += P V
        half8_t pf0 = *(const half8_t*)&Pt[l16 * 72 + quad * 8];
        half8_t pf1 = *(const half8_t*)&Pt[l16 * 72 + 32 + quad * 8];
        for (int t = 0; t < 8; t++) {
            half8_t v0 = *(const half8_t*)&Vs[(t * 16 + l16) * 72 + quad * 8];
            o[t] = MFMA16(pf0, v0, o[t]);
            half8_t v1 =
                *(const half8_t*)&Vs[(t * 16 + l16) * 72 + 32 + quad * 8];
            o[t] = MFMA16(pf1, v1, o[t]);
        }
    }

    float li0 = 1.0f / __shfl(l, quad * 4 + 0, 64);
    float li1 = 1.0f / __shfl(l, quad * 4 + 1, 64);
    float li2 = 1.0f / __shfl(l, quad * 4 + 2, 64);
    float li3 = 1.0f / __shfl(l, quad * 4 + 3, 64);
    size_t srow = (size_t)bb * 2048 + q0 + wave * 16 + quad * 4;
    for (int t = 0; t < 8; t++) {
        int d = t * 16 + l16;
        out[(srow + 0) * 128 + d] = o[t][0] * li0;
        out[(srow + 1) * 128 + d] = o[t][1] * li1;
        out[(srow + 2) * 128 + d] = o[t][2] * li2;
        out[(srow + 3) * 128 + d] = o[t][3] * li3;
    }
}

// ---------------------------------------------------------------------------
extern "C" void kernel_launch(void* const* d_in, const int* in_sizes, int n_in,
                              void* d_out, int out_size, void* d_ws,
                              size_t ws_size, hipStream_t stream) {
    const float* q_in = (const float*)d_in[0];
    const float* k_in = (const float*)d_in[1];
    const float* v_in = (const float*)d_in[2];
    const float* Wq = (const float*)d_in[3];
    const float* Wk = (const float*)d_in[4];
    const float* Wv = (const float*)d_in[5];
    const float* bq = (const float*)d_in[6];
    const float* bk = (const float*)d_in[7];
    const float* bv = (const float*)d_in[8];
    float* out = (float*)d_out;

    char* ws = (char*)d_ws;
    _Float16* WtAll = (_Float16*)ws;                    // 3 * 65536 * 2 B
    _Float16* qbuf  = (_Float16*)(ws + 393216);         // 16384*128*2 = 4 MB
    _Float16* kbuf  = (_Float16*)(ws + 4587520);        // 4 MB
    _Float16* vtbuf = (_Float16*)(ws + 8781824);        // 4 MB (transposed)

    wt_kernel<<<dim3(256, 3), 256, 0, stream>>>(Wq, Wk, Wv, WtAll);
    proj_kernel<<<dim3(128, 3), 256, 0, stream>>>(q_in, k_in, v_in, WtAll, bq,
                                                  bk, bv, qbuf, kbuf, vtbuf);
    attn_kernel<<<dim3(256), 256, 0, stream>>>(qbuf, kbuf, vtbuf, out);
}